// Round 9
// baseline (188.087 us; speedup 1.0000x reference)
//
#include <hip/hip_runtime.h>

#define TINYF 1e-8f
#define NITER 50

typedef __attribute__((ext_vector_type(2))) float v2f;

// Wave-wide DPP shifts (verified gfx950, R5-R8): 0x138 = wave_shr1 (lane i <- i-1,
// 0 into lane 0), 0x130 = wave_shl1 (lane i <- i+1, 0 into lane 63).
__device__ __forceinline__ float wWs(float v) {
    return __int_as_float(__builtin_amdgcn_update_dpp(0, __float_as_int(v), 0x138, 0xf, 0xf, true));
}
__device__ __forceinline__ float wEs(float v) {
    return __int_as_float(__builtin_amdgcn_update_dpp(0, __float_as_int(v), 0x130, 0xf, 0xf, true));
}
__device__ __forceinline__ v2f wW(v2f v) { v2f r; r.x = wWs(v.x); r.y = wWs(v.y); return r; }
__device__ __forceinline__ v2f wE(v2f v) { v2f r; r.x = wEs(v.x); r.y = wEs(v.y); return r; }
__device__ __forceinline__ v2f rcp2(v2f v) {
    v2f r; r.x = __builtin_amdgcn_rcpf(v.x); r.y = __builtin_amdgcn_rcpf(v.y); return r;
}
__device__ __forceinline__ v2f pfma(float k, v2f a, v2f c) {
    v2f kv; kv.x = k; kv.y = k;
    return __builtin_elementwise_fma(kv, a, c);
}

// R9: GHOST-ZONE exchange — ONE barrier per full Sinkhorn iteration.
// Layout (verified R6/R7): column-per-lane, 2-band packed, 4 waves = 1 crop.
// Wave W: .x = rows [6W,6W+6), .y = rows [24+6W,24+6W+6); lane l = column.
// Per iteration: read 4-row u-halos per side; compute v~ on rows -2..7
// (2 ghost rows/side, bit-identical to neighbor's own rows); compute u' on
// own rows purely from registers; publish u' 4-row halos; barrier.
// Tests the hypothesis that the ~1000ns fixed cost per sync epoch (invariant
// across R6-R8) dominates the wall: 51 epochs instead of 102 at +15% issue.
__global__ void __launch_bounds__(256)
sinkhorn_ghost(const float* __restrict__ hm_gt,
               const float* __restrict__ hm_pred,
               const int* __restrict__ tops,
               float* __restrict__ out) {
    // ES[parity][slot 0..5][8][64]; slot = W+1 for own writes.
    // rows 0..3 = own band rows 0,1,2,3 (wave above reads as +6..+9)
    // rows 4..7 = own band rows 2,3,4,5 (wave below reads as -4..-1)
    // Guards: slot0 rows4..7 .x = 0 (crop top); slot5 rows0..3 .y = 0 (bottom).
    // Seams: slot0 rows4..7 .y = crop rows 20..23 (W3 .x rows 2..5);
    //        slot5 rows0..3 .x = crop rows 24..27 (W0 .y rows 0..3).
    __shared__ v2f ES[2][6][8][64];
    __shared__ float sred[2][4];

    const int t = threadIdx.x;
    const int W = t >> 6;                  // wave 0..3
    const int l = t & 63;                  // column (0..47 active)
    const bool act = (l < 48);

    // zero guards for both parities (written once, never overwritten)
    {
        const int p = W >> 1;              // waves 0,1 -> parity 0; 2,3 -> 1
        const int j0 = (W & 1) * 2;
        ((float*)&ES[p][0][4 + j0][l])[0] = 0.f;
        ((float*)&ES[p][0][5 + j0][l])[0] = 0.f;
        ((float*)&ES[p][5][j0][l])[1] = 0.f;
        ((float*)&ES[p][5][j0 + 1][l])[1] = 0.f;
    }

    const int blk = blockIdx.x;            // ((bi*8+rr)*5+cc)
    const int bi = blk / 40, rr = (blk / 5) % 8, cc = blk % 5;
    const int y0 = tops[(bi * 8 + rr) * 2 + 0];
    const int x0 = tops[(bi * 8 + rr) * 2 + 1];
    const float* srcA = hm_gt + (size_t)(bi * 5 + cc) * 25600;
    const float* srcB = hm_pred + (size_t)(bi * 5 + cc) * 25600;

    // ---- load: a on own rows; b on extended rows -2..7 (ghost rows) ----
    v2f va[6], be[10];
    float sA = 0.f, sB = 0.f;
#pragma unroll
    for (int r = 0; r < 6; ++r) {
        const int gx = (y0 + 6 * W + r) * 160 + x0 + l;
        const int gy = (y0 + 24 + 6 * W + r) * 160 + x0 + l;
        va[r].x = act ? srcA[gx] : 0.f;
        va[r].y = act ? srcA[gy] : 0.f;
        sA += va[r].x + va[r].y;
    }
#pragma unroll
    for (int i = 0; i < 10; ++i) {
        const int cx = 6 * W + i - 2;          // crop row for .x  (<= 27)
        const int cy = 24 + 6 * W + i - 2;     // crop row for .y  (>= 22)
        const bool vx = (cx >= 0);
        const bool vy = (cy < 48);
        const int gx = (y0 + (vx ? cx : 0)) * 160 + x0 + l;
        const int gy = (y0 + (vy ? cy : 47)) * 160 + x0 + l;
        be[i].x = (act && vx) ? srcB[gx] : 0.f;
        be[i].y = (act && vy) ? srcB[gy] : 0.f;
        if (i >= 2 && i < 8) { sB += be[i].x + be[i].y; }  // own rows only
    }
#pragma unroll
    for (int o = 1; o < 64; o <<= 1) {
        sA += __shfl_xor(sA, o, 64);
        sB += __shfl_xor(sB, o, 64);
    }
    if (l == 0) { sred[0][W] = sA; sred[1][W] = sB; }
    __syncthreads();                       // also makes guard zeros visible
    sA = sred[0][0] + sred[0][1] + sred[0][2] + sred[0][3];
    sB = sred[1][0] + sred[1][1] + sred[1][2] + sred[1][3];
    const float nA = 1.0f / (sA + TINYF);
    const float nB = 1.0f / (sB + TINYF);
#pragma unroll
    for (int r = 0; r < 6; ++r) { va[r].x *= nA; va[r].y *= nA; }
#pragma unroll
    for (int i = 0; i < 10; ++i) { be[i].x *= nB; be[i].y *= nB; }

    // Gibbs weights (same expressions as the verified rounds -> same values)
    const float e10 = expf(-1.0f / 0.1f);
    const float e2  = expf(-sqrtf(2.0f) / 0.1f);
    const float e20 = expf(-2.0f / 0.1f);
    const v2f tiny = {TINYF, TINYF};

    v2f xu[6], vt[10];
    const float u0 = 1.0f / 2304.0f;
#pragma unroll
    for (int r = 0; r < 6; ++r) { xu[r].x = act ? u0 : 0.f; xu[r].y = act ? u0 : 0.f; }

    // publish current xu's 4-row halos (+ seams) into parity q
    auto publish = [&](int q) {
        ES[q][W + 1][0][l] = xu[0];
        ES[q][W + 1][1][l] = xu[1];
        ES[q][W + 1][2][l] = xu[2];
        ES[q][W + 1][3][l] = xu[3];
        ES[q][W + 1][4][l] = xu[2];
        ES[q][W + 1][5][l] = xu[3];
        ES[q][W + 1][6][l] = xu[4];
        ES[q][W + 1][7][l] = xu[5];
        if (W == 3) {   // crop rows 20..23 -> wave0 .y top halo
            ((float*)&ES[q][0][4][l])[1] = xu[2].x;
            ((float*)&ES[q][0][5][l])[1] = xu[3].x;
            ((float*)&ES[q][0][6][l])[1] = xu[4].x;
            ((float*)&ES[q][0][7][l])[1] = xu[5].x;
        }
        if (W == 0) {   // crop rows 24..27 -> wave3 .x bottom halo
            ((float*)&ES[q][5][0][l])[0] = xu[0].y;
            ((float*)&ES[q][5][1][l])[0] = xu[1].y;
            ((float*)&ES[q][5][2][l])[0] = xu[2].y;
            ((float*)&ES[q][5][3][l])[0] = xu[3].y;
        }
    };

    publish(0);
    __syncthreads();

    // ---- Sinkhorn iterations: ONE barrier per iteration ----
#pragma unroll 1
    for (int it = 0; it < NITER; ++it) {
        const int p = it & 1;
        // 8-row u halo
        v2f hu[4], hd[4];
#pragma unroll
        for (int j = 0; j < 4; ++j) {
            hu[j] = ES[p][W][4 + j][l];        // rows -4..-1
            hd[j] = ES[p][W + 2][j][l];        // rows +6..+9
        }
        auto uat = [&](int r) -> v2f {
            return (r < 0) ? hu[r + 4] : ((r < 6) ? xu[r] : hd[r - 6]);
        };
        // v~ on rows -2..7 (rolling horizontal prep; ghosts bit-exact)
        {
            v2f w1a = wW(uat(-3)), e1a = wE(uat(-3));
            v2f s1a = w1a + e1a;                  // s1[-3]
            v2f w1c = wW(uat(-2)), e1c = wE(uat(-2));
            v2f s1b = w1c + e1c;                  // s1[-2]
#pragma unroll
            for (int i = 0; i < 10; ++i) {
                const int r = i - 2;
                v2f w1n = wW(uat(r + 1)), e1n = wE(uat(r + 1));
                v2f s1n = w1n + e1n;              // s1[r+1]
                v2f s2c = wW(w1c) + wE(e1c);      // s2[r]
                v2f a = uat(r);
                a = pfma(e10, s1b + (uat(r - 1) + uat(r + 1)), a);
                a = pfma(e2,  s1a + s1n, a);
                a = pfma(e20, s2c + (uat(r - 2) + uat(r + 2)), a);
                vt[i] = be[i] * rcp2(a + tiny);
                s1a = s1b; s1b = s1n; w1c = w1n; e1c = e1n;
            }
        }
        // u' on own rows 0..5, fully from registers
        {
            v2f w1a = wW(vt[1]), e1a = wE(vt[1]);
            v2f s1a = w1a + e1a;                  // s1v[-1]
            v2f w1c = wW(vt[2]), e1c = wE(vt[2]);
            v2f s1b = w1c + e1c;                  // s1v[0]
#pragma unroll
            for (int r = 0; r < 6; ++r) {
                v2f w1n = wW(vt[r + 3]), e1n = wE(vt[r + 3]);
                v2f s1n = w1n + e1n;              // s1v[r+1]
                v2f s2c = wW(w1c) + wE(e1c);      // s2v[r]
                v2f a = vt[r + 2];
                a = pfma(e10, s1b + (vt[r + 1] + vt[r + 3]), a);
                a = pfma(e2,  s1a + s1n, a);
                a = pfma(e20, s2c + (vt[r] + vt[r + 4]), a);
                xu[r] = va[r] * rcp2(a + tiny);
                s1a = s1b; s1b = s1n; w1c = w1n; e1c = e1n;
            }
        }
        publish(p ^ 1);
        __syncthreads();
    }
    // final u halos are in parity (NITER & 1) ^ ... = parity 0; vt = final v~.

    // ---- loss: (u @ M) . v, M = K .* dist (center 0; e5/e8 taps dropped) ----
    const float s2f = sqrtf(2.0f);
    const float m01 = e10, m02 = e20 * 2.0f, m11 = e2 * s2f;
    v2f ls = {0.f, 0.f};
    {
        const v2f um2 = ES[0][W][6][l];        // row -2
        const v2f um1 = ES[0][W][7][l];        // row -1
        const v2f hp6 = ES[0][W + 2][0][l];    // row +6
        const v2f hp7 = ES[0][W + 2][1][l];    // row +7
        auto uat = [&](int r) -> v2f {
            return (r == -2) ? um2 : (r == -1) ? um1 :
                   (r == 6) ? hp6 : (r == 7) ? hp7 : xu[(r < 0) ? 0 : ((r > 5) ? 5 : r)];
        };
        v2f w1a = wW(um1), e1a = wE(um1);
        v2f s1a = w1a + e1a;                   // s1[-1]
        v2f w1c = wW(xu[0]), e1c = wE(xu[0]);
        v2f s1b = w1c + e1c;                   // s1[0]
        const v2f zero = {0.f, 0.f};
#pragma unroll
        for (int r = 0; r < 6; ++r) {
            v2f w1n = wW(uat(r + 1)), e1n = wE(uat(r + 1));
            v2f s1n = w1n + e1n;
            v2f s2c = wW(w1c) + wE(e1c);
            v2f a = pfma(m01, s1b + (uat(r - 1) + uat(r + 1)), zero);
            a = pfma(m11, s1a + s1n, a);
            a = pfma(m02, s2c + (uat(r - 2) + uat(r + 2)), a);
            ls += a * vt[r + 2];
            s1a = s1b; s1b = s1n; w1c = w1n; e1c = e1n;
        }
    }
    float lsum = ls.x + ls.y;

#pragma unroll
    for (int o = 1; o < 64; o <<= 1) lsum += __shfl_xor(lsum, o, 64);
    if (l == 0) sred[0][W] = lsum;
    __syncthreads();
    if (t == 0)
        atomicAdd(out, sred[0][0] + sred[0][1] + sred[0][2] + sred[0][3]);
}

extern "C" void kernel_launch(void* const* d_in, const int* in_sizes, int n_in,
                              void* d_out, int out_size, void* d_ws, size_t ws_size,
                              hipStream_t stream) {
    (void)in_sizes; (void)n_in; (void)out_size; (void)d_ws; (void)ws_size;
    const float* hm_gt = (const float*)d_in[0];
    const float* hm_pred = (const float*)d_in[1];
    const int* tops = (const int*)d_in[2];
    float* out = (float*)d_out;

    hipMemsetAsync(out, 0, sizeof(float), stream);
    sinkhorn_ghost<<<dim3(640), dim3(256), 0, stream>>>(hm_gt, hm_pred, tops, out);
}

// Round 10
// 167.800 us; speedup vs baseline: 1.1209x; 1.1209x over previous
//
#include <hip/hip_runtime.h>

#define TINYF 1e-8f
#define NITER 50

typedef __attribute__((ext_vector_type(2))) float v2f;

// Wave-wide DPP shifts (verified gfx950, R5-R9): 0x138 = wave_shr1 (lane i <- i-1,
// 0 into lane 0), 0x130 = wave_shl1 (lane i <- i+1, 0 into lane 63).
__device__ __forceinline__ float wWs(float v) {
    return __int_as_float(__builtin_amdgcn_update_dpp(0, __float_as_int(v), 0x138, 0xf, 0xf, true));
}
__device__ __forceinline__ float wEs(float v) {
    return __int_as_float(__builtin_amdgcn_update_dpp(0, __float_as_int(v), 0x130, 0xf, 0xf, true));
}
__device__ __forceinline__ v2f wW(v2f v) { v2f r; r.x = wWs(v.x); r.y = wWs(v.y); return r; }
__device__ __forceinline__ v2f wE(v2f v) { v2f r; r.x = wEs(v.x); r.y = wEs(v.y); return r; }
__device__ __forceinline__ v2f rcp2(v2f v) {
    v2f r; r.x = __builtin_amdgcn_rcpf(v.x); r.y = __builtin_amdgcn_rcpf(v.y); return r;
}
// Forced packed-f32 VOP3P ops (R10 experiment: defeat possible scalarization).
// Bit-exact vs two scalar ops; one instruction for both components.
__device__ __forceinline__ v2f padd(v2f a, v2f b) {
    v2f r; asm("v_pk_add_f32 %0, %1, %2" : "=v"(r) : "v"(a), "v"(b)); return r;
}
__device__ __forceinline__ v2f pmul(v2f a, v2f b) {
    v2f r; asm("v_pk_mul_f32 %0, %1, %2" : "=v"(r) : "v"(a), "v"(b)); return r;
}
__device__ __forceinline__ v2f pfma3(v2f a, v2f b, v2f c) {
    v2f r; asm("v_pk_fma_f32 %0, %1, %2, %3" : "=v"(r) : "v"(a), "v"(b), "v"(c)); return r;
}

// R10 = R7 (best verified structure, 115.7us) with ALL hot-loop v2f arithmetic
// forced to v_pk_*_f32 via inline asm. Layout: column-per-lane, 2-band packed,
// 4 waves = one 48x48 crop; wave W: .x = rows [6W,6W+6), .y = rows [24+6W,..).
// Pipelined half-iteration: combine+rcp fused (halo-free rows first), publish
// interleaved, DPP prep of the new field pre-barrier. 1 barrier/half-iter.
__global__ void __launch_bounds__(256)
sinkhorn_pk2(const float* __restrict__ hm_gt,
             const float* __restrict__ hm_pred,
             const int* __restrict__ tops,
             float* __restrict__ out) {
    __shared__ v2f ES[2][6][4][64];
    __shared__ float sred[2][4];

    const int t = threadIdx.x;
    const int W = t >> 6;                  // wave 0..3
    const int l = t & 63;                  // column (0..47 active)
    const bool act = (l < 48);

    // zero guards: .x of slot0 rows 2,3 (band -1) ; .y of slot5 rows 0,1 (band 8)
    {
        const int p = W >> 1, r = W & 1;
        ((float*)&ES[p][0][2 + r][l])[0] = 0.f;
        ((float*)&ES[p][5][r][l])[1] = 0.f;
    }

    const int blk = blockIdx.x;            // ((bi*8+rr)*5+cc)
    const int bi = blk / 40, rr = (blk / 5) % 8, cc = blk % 5;
    const int y0 = tops[(bi * 8 + rr) * 2 + 0];
    const int x0 = tops[(bi * 8 + rr) * 2 + 1];
    const float* srcA = hm_gt + (size_t)(bi * 5 + cc) * 25600;
    const float* srcB = hm_pred + (size_t)(bi * 5 + cc) * 25600;

    // ---- load own two 6-row column segments of both crops; block-reduce sums ----
    v2f va[6], vb[6];
    float sA = 0.f, sB = 0.f;
    const int rbx = y0 + 6 * W;            // .x band
    const int rby = y0 + 24 + 6 * W;       // .y band
#pragma unroll
    for (int r = 0; r < 6; ++r) {
        const int gx = (rbx + r) * 160 + x0 + l;
        const int gy = (rby + r) * 160 + x0 + l;
        va[r].x = act ? srcA[gx] : 0.f;
        va[r].y = act ? srcA[gy] : 0.f;
        vb[r].x = act ? srcB[gx] : 0.f;
        vb[r].y = act ? srcB[gy] : 0.f;
        sA += va[r].x + va[r].y;
        sB += vb[r].x + vb[r].y;
    }
#pragma unroll
    for (int o = 1; o < 64; o <<= 1) {
        sA += __shfl_xor(sA, o, 64);
        sB += __shfl_xor(sB, o, 64);
    }
    if (l == 0) { sred[0][W] = sA; sred[1][W] = sB; }
    __syncthreads();                       // also makes guard zeros visible
    sA = sred[0][0] + sred[0][1] + sred[0][2] + sred[0][3];
    sB = sred[1][0] + sred[1][1] + sred[1][2] + sred[1][3];
    const float nA = 1.0f / (sA + TINYF);
    const float nB = 1.0f / (sB + TINYF);
#pragma unroll
    for (int r = 0; r < 6; ++r) {
        va[r].x *= nA; va[r].y *= nA;
        vb[r].x *= nB; vb[r].y *= nB;
    }

    // Gibbs weights (same expressions as the verified rounds -> same values)
    const float e10 = expf(-1.0f / 0.1f);
    const float e2  = expf(-sqrtf(2.0f) / 0.1f);
    const float e20 = expf(-2.0f / 0.1f);
    const v2f tiny = {TINYF, TINYF};
    const v2f ke10 = {e10, e10};
    const v2f ke2  = {e2,  e2};
    const v2f ke20 = {e20, e20};

    v2f xu[6], xv[6];
    const float u0 = 1.0f / 2304.0f;
#pragma unroll
    for (int r = 0; r < 6; ++r) { xu[r].x = act ? u0 : 0.f; xu[r].y = act ? u0 : 0.f; }

    // horizontal prep arrays of the CURRENT field (live across the barrier)
    v2f s1o[6], s2o[6];
    auto prep = [&](const v2f (&x)[6]) {
#pragma unroll
        for (int r = 0; r < 6; ++r) {
            const v2f w1 = wW(x[r]), e1 = wE(x[r]);
            s1o[r] = padd(w1, e1);
            s2o[r] = padd(wW(w1), wE(e1));
        }
    };

    // One half-iteration (caller issues __syncthreads() after).
    auto half = [&](const v2f (&x)[6], v2f (&o)[6], const v2f (&co)[6],
                    int p, int q) {
        const v2f um1 = ES[p][W][3][l];        // band rows -1
        const v2f up6 = ES[p][W + 2][0][l];    // band rows +6
        const v2f um2 = ES[p][W][2][l];        // band rows -2
        const v2f up7 = ES[p][W + 2][1][l];    // band rows +7
        v2f a;
        // r=2 (halo-free)
        a = pfma3(ke10, padd(s1o[2], padd(x[1], x[3])), x[2]);
        a = pfma3(ke2,  padd(s1o[1], s1o[3]), a);
        a = pfma3(ke20, padd(s2o[2], padd(x[0], x[4])), a);
        o[2] = pmul(co[2], rcp2(padd(a, tiny)));
        // r=3 (halo-free)
        a = pfma3(ke10, padd(s1o[3], padd(x[2], x[4])), x[3]);
        a = pfma3(ke2,  padd(s1o[2], s1o[4]), a);
        a = pfma3(ke20, padd(s2o[3], padd(x[1], x[5])), a);
        o[3] = pmul(co[3], rcp2(padd(a, tiny)));
        // r=1 (needs um1)
        a = pfma3(ke10, padd(s1o[1], padd(x[0], x[2])), x[1]);
        a = pfma3(ke2,  padd(s1o[0], s1o[2]), a);
        a = pfma3(ke20, padd(s2o[1], padd(um1, x[3])), a);
        o[1] = pmul(co[1], rcp2(padd(a, tiny)));
        ES[q][W + 1][1][l] = o[1];
        // r=4 (needs up6)
        a = pfma3(ke10, padd(s1o[4], padd(x[3], x[5])), x[4]);
        a = pfma3(ke2,  padd(s1o[3], s1o[5]), a);
        a = pfma3(ke20, padd(s2o[4], padd(x[2], up6)), a);
        o[4] = pmul(co[4], rcp2(padd(a, tiny)));
        ES[q][W + 1][2][l] = o[4];
        // halo horizontal sums for rows 0,5
        const v2f s1m = padd(wW(um1), wE(um1));
        const v2f s1p = padd(wW(up6), wE(up6));
        // r=0
        a = pfma3(ke10, padd(s1o[0], padd(um1, x[1])), x[0]);
        a = pfma3(ke2,  padd(s1m, s1o[1]), a);
        a = pfma3(ke20, padd(s2o[0], padd(um2, x[2])), a);
        o[0] = pmul(co[0], rcp2(padd(a, tiny)));
        ES[q][W + 1][0][l] = o[0];
        // r=5
        a = pfma3(ke10, padd(s1o[5], padd(x[4], up6)), x[5]);
        a = pfma3(ke2,  padd(s1o[4], s1p), a);
        a = pfma3(ke20, padd(s2o[5], padd(x[3], up7)), a);
        o[5] = pmul(co[5], rcp2(padd(a, tiny)));
        ES[q][W + 1][3][l] = o[5];
        // seams (band3<->band4)
        if (W == 3) {
            ((float*)&ES[q][0][2][l])[1] = o[4].x;
            ((float*)&ES[q][0][3][l])[1] = o[5].x;
        }
        if (W == 0) {
            ((float*)&ES[q][5][0][l])[0] = o[0].y;
            ((float*)&ES[q][5][1][l])[0] = o[1].y;
        }
        // prep of the new field BEFORE the barrier (pure VALU, hides drain/skew)
        prep(o);
    };

    // seed parity 0 with u0 boundary rows; prep(xu); sync
    {
        ES[0][W + 1][0][l] = xu[0];
        ES[0][W + 1][1][l] = xu[1];
        ES[0][W + 1][2][l] = xu[4];
        ES[0][W + 1][3][l] = xu[5];
        if (W == 3) {
            ((float*)&ES[0][0][2][l])[1] = xu[4].x;
            ((float*)&ES[0][0][3][l])[1] = xu[5].x;
        }
        if (W == 0) {
            ((float*)&ES[0][5][0][l])[0] = xu[0].y;
            ((float*)&ES[0][5][1][l])[0] = xu[1].y;
        }
        prep(xu);
        __syncthreads();
    }

    // ---- Sinkhorn iterations: 1 barrier per half-iteration, pipelined ----
#pragma unroll 1
    for (int it = 0; it < NITER; ++it) {
        half(xu, xv, vb, 0, 1);
        __syncthreads();
        half(xv, xu, va, 1, 0);
        __syncthreads();
    }

    // ---- loss: (u @ M) . v, M = K .* dist (center 0; e5/e8 taps dropped) ----
    // Uses s1o/s2o = prep(xu) from the final half; halos from parity 0.
    const float s2f = sqrtf(2.0f);
    const v2f km01 = {e10, e10};
    const v2f km02 = {e20 * 2.0f, e20 * 2.0f};
    const v2f km11 = {e2 * s2f, e2 * s2f};
    v2f ls = {0.f, 0.f};
    {
        const v2f um1 = ES[0][W][3][l];
        const v2f up6 = ES[0][W + 2][0][l];
        const v2f um2 = ES[0][W][2][l];
        const v2f up7 = ES[0][W + 2][1][l];
        const v2f s1m = padd(wW(um1), wE(um1));
        const v2f s1p = padd(wW(up6), wE(up6));
        v2f a;
        // r=0
        a = pmul(km01, padd(s1o[0], padd(um1, xu[1])));
        a = pfma3(km11, padd(s1m, s1o[1]), a);
        a = pfma3(km02, padd(s2o[0], padd(um2, xu[2])), a);
        ls = pfma3(a, xv[0], ls);
        // r=1
        a = pmul(km01, padd(s1o[1], padd(xu[0], xu[2])));
        a = pfma3(km11, padd(s1o[0], s1o[2]), a);
        a = pfma3(km02, padd(s2o[1], padd(um1, xu[3])), a);
        ls = pfma3(a, xv[1], ls);
        // r=2
        a = pmul(km01, padd(s1o[2], padd(xu[1], xu[3])));
        a = pfma3(km11, padd(s1o[1], s1o[3]), a);
        a = pfma3(km02, padd(s2o[2], padd(xu[0], xu[4])), a);
        ls = pfma3(a, xv[2], ls);
        // r=3
        a = pmul(km01, padd(s1o[3], padd(xu[2], xu[4])));
        a = pfma3(km11, padd(s1o[2], s1o[4]), a);
        a = pfma3(km02, padd(s2o[3], padd(xu[1], xu[5])), a);
        ls = pfma3(a, xv[3], ls);
        // r=4
        a = pmul(km01, padd(s1o[4], padd(xu[3], xu[5])));
        a = pfma3(km11, padd(s1o[3], s1o[5]), a);
        a = pfma3(km02, padd(s2o[4], padd(xu[2], up6)), a);
        ls = pfma3(a, xv[4], ls);
        // r=5
        a = pmul(km01, padd(s1o[5], padd(xu[4], up6)));
        a = pfma3(km11, padd(s1o[4], s1p), a);
        a = pfma3(km02, padd(s2o[5], padd(xu[3], up7)), a);
        ls = pfma3(a, xv[5], ls);
    }
    float lsum = ls.x + ls.y;

#pragma unroll
    for (int o = 1; o < 64; o <<= 1) lsum += __shfl_xor(lsum, o, 64);
    if (l == 0) sred[0][W] = lsum;
    __syncthreads();
    if (t == 0)
        atomicAdd(out, sred[0][0] + sred[0][1] + sred[0][2] + sred[0][3]);
}

extern "C" void kernel_launch(void* const* d_in, const int* in_sizes, int n_in,
                              void* d_out, int out_size, void* d_ws, size_t ws_size,
                              hipStream_t stream) {
    (void)in_sizes; (void)n_in; (void)out_size; (void)d_ws; (void)ws_size;
    const float* hm_gt = (const float*)d_in[0];
    const float* hm_pred = (const float*)d_in[1];
    const int* tops = (const int*)d_in[2];
    float* out = (float*)d_out;

    hipMemsetAsync(out, 0, sizeof(float), stream);
    sinkhorn_pk2<<<dim3(640), dim3(256), 0, stream>>>(hm_gt, hm_pred, tops, out);
}

// Round 11
// 167.576 us; speedup vs baseline: 1.1224x; 1.0013x over previous
//
#include <hip/hip_runtime.h>

#define TINYF 1e-8f
#define NITER 50

typedef __attribute__((ext_vector_type(2))) float v2f;

// Wave-wide DPP shifts (verified gfx950, R5-R10): 0x138 = wave_shr1 (lane i <- i-1,
// 0 into lane 0), 0x130 = wave_shl1 (lane i <- i+1, 0 into lane 63).
__device__ __forceinline__ float wWs(float v) {
    return __int_as_float(__builtin_amdgcn_update_dpp(0, __float_as_int(v), 0x138, 0xf, 0xf, true));
}
__device__ __forceinline__ float wEs(float v) {
    return __int_as_float(__builtin_amdgcn_update_dpp(0, __float_as_int(v), 0x130, 0xf, 0xf, true));
}
__device__ __forceinline__ v2f wW(v2f v) { v2f r; r.x = wWs(v.x); r.y = wWs(v.y); return r; }
__device__ __forceinline__ v2f wE(v2f v) { v2f r; r.x = wEs(v.x); r.y = wEs(v.y); return r; }
__device__ __forceinline__ v2f rcp2(v2f v) {
    v2f r; r.x = __builtin_amdgcn_rcpf(v.x); r.y = __builtin_amdgcn_rcpf(v.y); return r;
}
__device__ __forceinline__ v2f pfma(float k, v2f a, v2f c) {
    v2f kv; kv.x = k; kv.y = k;
    return __builtin_elementwise_fma(kv, a, c);
}

// R11 = R7 (best, 115.7us) + PHASE STAGGER. Model (fits R7/R8 to <1%):
// wall/epoch = heavy-CU issue / (4 SIMDs x 0.70). The 0.70 ceiling is
// hypothesized to be phase-locked co-resident blocks (all barrier-waits
// align). Blocks sharing a CU differ by 256 in blockIdx.x (round-robin
// dispatch), so a one-time s_sleep keyed on blockIdx.x>>8 staggers the
// three co-residency rounds by ~1/3 period each. Bit-identical arithmetic.
__global__ void __launch_bounds__(256)
sinkhorn_stag(const float* __restrict__ hm_gt,
              const float* __restrict__ hm_pred,
              const int* __restrict__ tops,
              float* __restrict__ out) {
    __shared__ v2f ES[2][6][4][64];
    __shared__ float sred[2][4];

    const int t = threadIdx.x;
    const int W = t >> 6;                  // wave 0..3
    const int l = t & 63;                  // column (0..47 active)
    const bool act = (l < 48);

    // zero guards: .x of slot0 rows 2,3 (band -1) ; .y of slot5 rows 0,1 (band 8)
    {
        const int p = W >> 1, r = W & 1;
        ((float*)&ES[p][0][2 + r][l])[0] = 0.f;
        ((float*)&ES[p][5][r][l])[1] = 0.f;
    }

    const int blk = blockIdx.x;            // ((bi*8+rr)*5+cc)
    const int bi = blk / 40, rr = (blk / 5) % 8, cc = blk % 5;
    const int y0 = tops[(bi * 8 + rr) * 2 + 0];
    const int x0 = tops[(bi * 8 + rr) * 2 + 1];
    const float* srcA = hm_gt + (size_t)(bi * 5 + cc) * 25600;
    const float* srcB = hm_pred + (size_t)(bi * 5 + cc) * 25600;

    // ---- load own two 6-row column segments of both crops; block-reduce sums ----
    v2f va[6], vb[6];
    float sA = 0.f, sB = 0.f;
    const int rbx = y0 + 6 * W;            // .x band
    const int rby = y0 + 24 + 6 * W;       // .y band
#pragma unroll
    for (int r = 0; r < 6; ++r) {
        const int gx = (rbx + r) * 160 + x0 + l;
        const int gy = (rby + r) * 160 + x0 + l;
        va[r].x = act ? srcA[gx] : 0.f;
        va[r].y = act ? srcA[gy] : 0.f;
        vb[r].x = act ? srcB[gx] : 0.f;
        vb[r].y = act ? srcB[gy] : 0.f;
        sA += va[r].x + va[r].y;
        sB += vb[r].x + vb[r].y;
    }
#pragma unroll
    for (int o = 1; o < 64; o <<= 1) {
        sA += __shfl_xor(sA, o, 64);
        sB += __shfl_xor(sB, o, 64);
    }
    if (l == 0) { sred[0][W] = sA; sred[1][W] = sB; }
    __syncthreads();                       // also makes guard zeros visible
    sA = sred[0][0] + sred[0][1] + sred[0][2] + sred[0][3];
    sB = sred[1][0] + sred[1][1] + sred[1][2] + sred[1][3];
    const float nA = 1.0f / (sA + TINYF);
    const float nB = 1.0f / (sB + TINYF);
#pragma unroll
    for (int r = 0; r < 6; ++r) {
        va[r].x *= nA; va[r].y *= nA;
        vb[r].x *= nB; vb[r].y *= nB;
    }

    // Gibbs weights (same expressions as the verified rounds -> same values)
    const float e10 = expf(-1.0f / 0.1f);
    const float e2  = expf(-sqrtf(2.0f) / 0.1f);
    const float e20 = expf(-2.0f / 0.1f);
    const v2f tiny = {TINYF, TINYF};

    v2f xu[6], xv[6];
    const float u0 = 1.0f / 2304.0f;
#pragma unroll
    for (int r = 0; r < 6; ++r) { xu[r].x = act ? u0 : 0.f; xu[r].y = act ? u0 : 0.f; }

    // horizontal prep arrays of the CURRENT field (live across the barrier)
    v2f s1o[6], s2o[6];
    auto prep = [&](const v2f (&x)[6]) {
#pragma unroll
        for (int r = 0; r < 6; ++r) {
            const v2f w1 = wW(x[r]), e1 = wE(x[r]);
            s1o[r] = w1 + e1;
            s2o[r] = wW(w1) + wE(e1);
        }
    };

    // One half-iteration (caller issues __syncthreads() after).
    auto half = [&](const v2f (&x)[6], v2f (&o)[6], const v2f (&co)[6],
                    int p, int q) {
        const v2f um1 = ES[p][W][3][l];        // band rows -1
        const v2f up6 = ES[p][W + 2][0][l];    // band rows +6
        const v2f um2 = ES[p][W][2][l];        // band rows -2
        const v2f up7 = ES[p][W + 2][1][l];    // band rows +7
        v2f a;
        // r=2 (halo-free)
        a = x[2];
        a = pfma(e10, s1o[2] + (x[1] + x[3]), a);
        a = pfma(e2,  s1o[1] + s1o[3], a);
        a = pfma(e20, s2o[2] + (x[0] + x[4]), a);
        o[2] = co[2] * rcp2(a + tiny);
        // r=3 (halo-free)
        a = x[3];
        a = pfma(e10, s1o[3] + (x[2] + x[4]), a);
        a = pfma(e2,  s1o[2] + s1o[4], a);
        a = pfma(e20, s2o[3] + (x[1] + x[5]), a);
        o[3] = co[3] * rcp2(a + tiny);
        // r=1 (needs um1)
        a = x[1];
        a = pfma(e10, s1o[1] + (x[0] + x[2]), a);
        a = pfma(e2,  s1o[0] + s1o[2], a);
        a = pfma(e20, s2o[1] + (um1 + x[3]), a);
        o[1] = co[1] * rcp2(a + tiny);
        ES[q][W + 1][1][l] = o[1];
        // r=4 (needs up6)
        a = x[4];
        a = pfma(e10, s1o[4] + (x[3] + x[5]), a);
        a = pfma(e2,  s1o[3] + s1o[5], a);
        a = pfma(e20, s2o[4] + (x[2] + up6), a);
        o[4] = co[4] * rcp2(a + tiny);
        ES[q][W + 1][2][l] = o[4];
        // halo horizontal sums for rows 0,5
        const v2f s1m = wW(um1) + wE(um1);
        const v2f s1p = wW(up6) + wE(up6);
        // r=0
        a = x[0];
        a = pfma(e10, s1o[0] + (um1 + x[1]), a);
        a = pfma(e2,  s1m + s1o[1], a);
        a = pfma(e20, s2o[0] + (um2 + x[2]), a);
        o[0] = co[0] * rcp2(a + tiny);
        ES[q][W + 1][0][l] = o[0];
        // r=5
        a = x[5];
        a = pfma(e10, s1o[5] + (x[4] + up6), a);
        a = pfma(e2,  s1o[4] + s1p, a);
        a = pfma(e20, s2o[5] + (x[3] + up7), a);
        o[5] = co[5] * rcp2(a + tiny);
        ES[q][W + 1][3][l] = o[5];
        // seams (band3<->band4)
        if (W == 3) {
            ((float*)&ES[q][0][2][l])[1] = o[4].x;
            ((float*)&ES[q][0][3][l])[1] = o[5].x;
        }
        if (W == 0) {
            ((float*)&ES[q][5][0][l])[0] = o[0].y;
            ((float*)&ES[q][5][1][l])[0] = o[1].y;
        }
        // prep of the new field BEFORE the barrier (pure VALU, hides drain/skew)
        prep(o);
    };

    // ---- PHASE STAGGER: de-phase the 3 co-residency rounds (blk>>8 = 0,1,2).
    // s_sleep units are 64 clocks: 14 ~ 900 cyc ~ 1/3 of the 2768-cyc epoch.
    {
        const int ph = blk >> 8;
        if (ph == 1)      __builtin_amdgcn_s_sleep(14);
        else if (ph == 2) __builtin_amdgcn_s_sleep(28);
    }

    // seed parity 0 with u0 boundary rows; prep(xu); sync
    {
        ES[0][W + 1][0][l] = xu[0];
        ES[0][W + 1][1][l] = xu[1];
        ES[0][W + 1][2][l] = xu[4];
        ES[0][W + 1][3][l] = xu[5];
        if (W == 3) {
            ((float*)&ES[0][0][2][l])[1] = xu[4].x;
            ((float*)&ES[0][0][3][l])[1] = xu[5].x;
        }
        if (W == 0) {
            ((float*)&ES[0][5][0][l])[0] = xu[0].y;
            ((float*)&ES[0][5][1][l])[0] = xu[1].y;
        }
        prep(xu);
        __syncthreads();
    }

    // ---- Sinkhorn iterations: 1 barrier per half-iteration, pipelined ----
#pragma unroll 1
    for (int it = 0; it < NITER; ++it) {
        half(xu, xv, vb, 0, 1);
        __syncthreads();
        half(xv, xu, va, 1, 0);
        __syncthreads();
    }

    // ---- loss: (u @ M) . v, M = K .* dist (center 0; e5/e8 taps dropped) ----
    // Uses s1o/s2o = prep(xu) from the final half; halos from parity 0.
    const float s2f = sqrtf(2.0f);
    const float m01 = e10, m02 = e20 * 2.0f, m11 = e2 * s2f;
    v2f ls = {0.f, 0.f};
    {
        const v2f um1 = ES[0][W][3][l];
        const v2f up6 = ES[0][W + 2][0][l];
        const v2f um2 = ES[0][W][2][l];
        const v2f up7 = ES[0][W + 2][1][l];
        const v2f s1m = wW(um1) + wE(um1);
        const v2f s1p = wW(up6) + wE(up6);
        const v2f zero = {0.f, 0.f};
        v2f a;
        // r=0
        a = pfma(m01, s1o[0] + (um1 + xu[1]), zero);
        a = pfma(m11, s1m + s1o[1], a);
        a = pfma(m02, s2o[0] + (um2 + xu[2]), a);
        ls += a * xv[0];
        // r=1
        a = pfma(m01, s1o[1] + (xu[0] + xu[2]), zero);
        a = pfma(m11, s1o[0] + s1o[2], a);
        a = pfma(m02, s2o[1] + (um1 + xu[3]), a);
        ls += a * xv[1];
        // r=2
        a = pfma(m01, s1o[2] + (xu[1] + xu[3]), zero);
        a = pfma(m11, s1o[1] + s1o[3], a);
        a = pfma(m02, s2o[2] + (xu[0] + xu[4]), a);
        ls += a * xv[2];
        // r=3
        a = pfma(m01, s1o[3] + (xu[2] + xu[4]), zero);
        a = pfma(m11, s1o[2] + s1o[4], a);
        a = pfma(m02, s2o[3] + (xu[1] + xu[5]), a);
        ls += a * xv[3];
        // r=4
        a = pfma(m01, s1o[4] + (xu[3] + xu[5]), zero);
        a = pfma(m11, s1o[3] + s1o[5], a);
        a = pfma(m02, s2o[4] + (xu[2] + up6), a);
        ls += a * xv[4];
        // r=5
        a = pfma(m01, s1o[5] + (xu[4] + up6), zero);
        a = pfma(m11, s1o[4] + s1p, a);
        a = pfma(m02, s2o[5] + (xu[3] + up7), a);
        ls += a * xv[5];
    }
    float lsum = ls.x + ls.y;

#pragma unroll
    for (int o = 1; o < 64; o <<= 1) lsum += __shfl_xor(lsum, o, 64);
    if (l == 0) sred[0][W] = lsum;
    __syncthreads();
    if (t == 0)
        atomicAdd(out, sred[0][0] + sred[0][1] + sred[0][2] + sred[0][3]);
}

extern "C" void kernel_launch(void* const* d_in, const int* in_sizes, int n_in,
                              void* d_out, int out_size, void* d_ws, size_t ws_size,
                              hipStream_t stream) {
    (void)in_sizes; (void)n_in; (void)out_size; (void)d_ws; (void)ws_size;
    const float* hm_gt = (const float*)d_in[0];
    const float* hm_pred = (const float*)d_in[1];
    const int* tops = (const int*)d_in[2];
    float* out = (float*)d_out;

    hipMemsetAsync(out, 0, sizeof(float), stream);
    sinkhorn_stag<<<dim3(640), dim3(256), 0, stream>>>(hm_gt, hm_pred, tops, out);
}

// Round 12
// 166.956 us; speedup vs baseline: 1.1266x; 1.0037x over previous
//
#include <hip/hip_runtime.h>

#define TINYF 1e-8f
#define NITER 50

typedef __attribute__((ext_vector_type(2))) float v2f;

// Wave-wide DPP shifts (verified gfx950, R5-R11): 0x138 = wave_shr1 (lane i <- i-1,
// 0 into lane 0), 0x130 = wave_shl1 (lane i <- i+1, 0 into lane 63).
__device__ __forceinline__ float wWs(float v) {
    return __int_as_float(__builtin_amdgcn_update_dpp(0, __float_as_int(v), 0x138, 0xf, 0xf, true));
}
__device__ __forceinline__ float wEs(float v) {
    return __int_as_float(__builtin_amdgcn_update_dpp(0, __float_as_int(v), 0x130, 0xf, 0xf, true));
}
__device__ __forceinline__ v2f wW(v2f v) { v2f r; r.x = wWs(v.x); r.y = wWs(v.y); return r; }
__device__ __forceinline__ v2f wE(v2f v) { v2f r; r.x = wEs(v.x); r.y = wEs(v.y); return r; }
__device__ __forceinline__ v2f rcp2(v2f v) {
    v2f r; r.x = __builtin_amdgcn_rcpf(v.x); r.y = __builtin_amdgcn_rcpf(v.y); return r;
}
__device__ __forceinline__ v2f pfma(float k, v2f a, v2f c) {
    v2f kv; kv.x = k; kv.y = k;
    return __builtin_elementwise_fma(kv, a, c);
}

// R12 = R7 structure with STAGE-INTERLEAVED math + register headroom.
// Insight chain: co-resident blocks phase-lock (R11: stagger decays -> lock is
// an attractor), so dependency bubbles are correlated across all resident
// waves and TLP cannot fill them. VGPR=48 shows the compiler serialized the
// six per-row chains to minimize registers. Fix: reorder (bit-exact per
// element) so each pipeline stage is 6 independent chains, and allow VGPR
// growth via waves_per_eu(3,4) (heavy CU only ever holds 3 waves/SIMD).
__global__ void __launch_bounds__(256)
__attribute__((amdgpu_waves_per_eu(3, 4)))
sinkhorn_ilp(const float* __restrict__ hm_gt,
             const float* __restrict__ hm_pred,
             const int* __restrict__ tops,
             float* __restrict__ out) {
    __shared__ v2f ES[2][6][4][64];
    __shared__ float sred[2][4];

    const int t = threadIdx.x;
    const int W = t >> 6;                  // wave 0..3
    const int l = t & 63;                  // column (0..47 active)
    const bool act = (l < 48);

    // zero guards: .x of slot0 rows 2,3 (band -1) ; .y of slot5 rows 0,1 (band 8)
    {
        const int p = W >> 1, r = W & 1;
        ((float*)&ES[p][0][2 + r][l])[0] = 0.f;
        ((float*)&ES[p][5][r][l])[1] = 0.f;
    }

    const int blk = blockIdx.x;            // ((bi*8+rr)*5+cc)
    const int bi = blk / 40, rr = (blk / 5) % 8, cc = blk % 5;
    const int y0 = tops[(bi * 8 + rr) * 2 + 0];
    const int x0 = tops[(bi * 8 + rr) * 2 + 1];
    const float* srcA = hm_gt + (size_t)(bi * 5 + cc) * 25600;
    const float* srcB = hm_pred + (size_t)(bi * 5 + cc) * 25600;

    // ---- load own two 6-row column segments of both crops; block-reduce sums ----
    v2f va[6], vb[6];
    float sA = 0.f, sB = 0.f;
    const int rbx = y0 + 6 * W;            // .x band
    const int rby = y0 + 24 + 6 * W;       // .y band
#pragma unroll
    for (int r = 0; r < 6; ++r) {
        const int gx = (rbx + r) * 160 + x0 + l;
        const int gy = (rby + r) * 160 + x0 + l;
        va[r].x = act ? srcA[gx] : 0.f;
        va[r].y = act ? srcA[gy] : 0.f;
        vb[r].x = act ? srcB[gx] : 0.f;
        vb[r].y = act ? srcB[gy] : 0.f;
        sA += va[r].x + va[r].y;
        sB += vb[r].x + vb[r].y;
    }
#pragma unroll
    for (int o = 1; o < 64; o <<= 1) {
        sA += __shfl_xor(sA, o, 64);
        sB += __shfl_xor(sB, o, 64);
    }
    if (l == 0) { sred[0][W] = sA; sred[1][W] = sB; }
    __syncthreads();                       // also makes guard zeros visible
    sA = sred[0][0] + sred[0][1] + sred[0][2] + sred[0][3];
    sB = sred[1][0] + sred[1][1] + sred[1][2] + sred[1][3];
    const float nA = 1.0f / (sA + TINYF);
    const float nB = 1.0f / (sB + TINYF);
#pragma unroll
    for (int r = 0; r < 6; ++r) {
        va[r].x *= nA; va[r].y *= nA;
        vb[r].x *= nB; vb[r].y *= nB;
    }

    // Gibbs weights (same expressions as the verified rounds -> same values)
    const float e10 = expf(-1.0f / 0.1f);
    const float e2  = expf(-sqrtf(2.0f) / 0.1f);
    const float e20 = expf(-2.0f / 0.1f);
    const v2f tiny = {TINYF, TINYF};

    v2f xu[6], xv[6];
    const float u0 = 1.0f / 2304.0f;
#pragma unroll
    for (int r = 0; r < 6; ++r) { xu[r].x = act ? u0 : 0.f; xu[r].y = act ? u0 : 0.f; }

    // horizontal prep arrays of the CURRENT field (live across the barrier).
    // Stage-interleaved: 12 indep DPP, 6 adds, 12 indep DPP, 6 adds.
    v2f s1o[6], s2o[6];
    auto prep = [&](const v2f (&x)[6]) {
        v2f w1[6], e1[6];
#pragma unroll
        for (int r = 0; r < 6; ++r) { w1[r] = wW(x[r]); e1[r] = wE(x[r]); }
#pragma unroll
        for (int r = 0; r < 6; ++r) s1o[r] = w1[r] + e1[r];
        v2f w2[6], e2v[6];
#pragma unroll
        for (int r = 0; r < 6; ++r) { w2[r] = wW(w1[r]); e2v[r] = wE(e1[r]); }
#pragma unroll
        for (int r = 0; r < 6; ++r) s2o[r] = w2[r] + e2v[r];
    };

    // One half-iteration (caller issues __syncthreads() after). Stage form:
    // every stage = 6 independent chains -> dep latency hidden by in-wave ILP
    // even under cross-block phase-lock. Bit-exact per-element vs R7.
    auto half = [&](const v2f (&x)[6], v2f (&o)[6], const v2f (&co)[6],
                    int p, int q) {
        const v2f um1 = ES[p][W][3][l];        // band rows -1
        const v2f up6 = ES[p][W + 2][0][l];    // band rows +6
        const v2f um2 = ES[p][W][2][l];        // band rows -2
        const v2f up7 = ES[p][W + 2][1][l];    // band rows +7
        // S1: |dy|=1 vertical sums (x-only rows first: covers LDS latency)
        const v2f u1 = x[0] + x[2];
        const v2f u2 = x[1] + x[3];
        const v2f u3 = x[2] + x[4];
        const v2f u4 = x[3] + x[5];
        const v2f u0 = um1 + x[1];
        const v2f u5 = x[4] + up6;
        // halo horizontal sums (dep on um1/up6; 4 indep DPP + 2 adds)
        const v2f s1m = wW(um1) + wE(um1);
        const v2f s1p = wW(up6) + wE(up6);
        // S2: e10 level, 6 independent
        v2f a0, a1, a2, a3, a4, a5;
        a1 = pfma(e10, s1o[1] + u1, x[1]);
        a2 = pfma(e10, s1o[2] + u2, x[2]);
        a3 = pfma(e10, s1o[3] + u3, x[3]);
        a4 = pfma(e10, s1o[4] + u4, x[4]);
        a0 = pfma(e10, s1o[0] + u0, x[0]);
        a5 = pfma(e10, s1o[5] + u5, x[5]);
        // S3: e2 diagonal level, 6 independent
        a1 = pfma(e2, s1o[0] + s1o[2], a1);
        a2 = pfma(e2, s1o[1] + s1o[3], a2);
        a3 = pfma(e2, s1o[2] + s1o[4], a3);
        a4 = pfma(e2, s1o[3] + s1o[5], a4);
        a0 = pfma(e2, s1m + s1o[1], a0);
        a5 = pfma(e2, s1o[4] + s1p, a5);
        // S4: e20 level, 6 independent
        a1 = pfma(e20, s2o[1] + (um1 + x[3]), a1);
        a2 = pfma(e20, s2o[2] + (x[0] + x[4]), a2);
        a3 = pfma(e20, s2o[3] + (x[1] + x[5]), a3);
        a4 = pfma(e20, s2o[4] + (x[2] + up6), a4);
        a0 = pfma(e20, s2o[0] + (um2 + x[2]), a0);
        a5 = pfma(e20, s2o[5] + (x[3] + up7), a5);
        // S5: +tiny (6 indep), 12 back-to-back rcp, 6 muls
        a0 = a0 + tiny; a1 = a1 + tiny; a2 = a2 + tiny;
        a3 = a3 + tiny; a4 = a4 + tiny; a5 = a5 + tiny;
        const v2f r0 = rcp2(a0), r1 = rcp2(a1), r2 = rcp2(a2);
        const v2f r3 = rcp2(a3), r4 = rcp2(a4), r5 = rcp2(a5);
        o[0] = co[0] * r0; o[1] = co[1] * r1; o[2] = co[2] * r2;
        o[3] = co[3] * r3; o[4] = co[4] * r4; o[5] = co[5] * r5;
        // publish boundary rows (+ seams) to parity q
        ES[q][W + 1][0][l] = o[0];
        ES[q][W + 1][1][l] = o[1];
        ES[q][W + 1][2][l] = o[4];
        ES[q][W + 1][3][l] = o[5];
        if (W == 3) {
            ((float*)&ES[q][0][2][l])[1] = o[4].x;
            ((float*)&ES[q][0][3][l])[1] = o[5].x;
        }
        if (W == 0) {
            ((float*)&ES[q][5][0][l])[0] = o[0].y;
            ((float*)&ES[q][5][1][l])[0] = o[1].y;
        }
        // prep of the new field BEFORE the barrier (pure VALU, hides drain/skew)
        prep(o);
    };

    // seed parity 0 with u0 boundary rows; prep(xu); sync
    {
        ES[0][W + 1][0][l] = xu[0];
        ES[0][W + 1][1][l] = xu[1];
        ES[0][W + 1][2][l] = xu[4];
        ES[0][W + 1][3][l] = xu[5];
        if (W == 3) {
            ((float*)&ES[0][0][2][l])[1] = xu[4].x;
            ((float*)&ES[0][0][3][l])[1] = xu[5].x;
        }
        if (W == 0) {
            ((float*)&ES[0][5][0][l])[0] = xu[0].y;
            ((float*)&ES[0][5][1][l])[0] = xu[1].y;
        }
        prep(xu);
        __syncthreads();
    }

    // ---- Sinkhorn iterations: 1 barrier per half-iteration, pipelined ----
#pragma unroll 1
    for (int it = 0; it < NITER; ++it) {
        half(xu, xv, vb, 0, 1);
        __syncthreads();
        half(xv, xu, va, 1, 0);
        __syncthreads();
    }

    // ---- loss: (u @ M) . v, M = K .* dist (center 0; e5/e8 taps dropped) ----
    // Uses s1o/s2o = prep(xu) from the final half; halos from parity 0.
    const float s2f = sqrtf(2.0f);
    const float m01 = e10, m02 = e20 * 2.0f, m11 = e2 * s2f;
    v2f ls = {0.f, 0.f};
    {
        const v2f um1 = ES[0][W][3][l];
        const v2f up6 = ES[0][W + 2][0][l];
        const v2f um2 = ES[0][W][2][l];
        const v2f up7 = ES[0][W + 2][1][l];
        const v2f s1m = wW(um1) + wE(um1);
        const v2f s1p = wW(up6) + wE(up6);
        const v2f zero = {0.f, 0.f};
        v2f a;
        // r=0
        a = pfma(m01, s1o[0] + (um1 + xu[1]), zero);
        a = pfma(m11, s1m + s1o[1], a);
        a = pfma(m02, s2o[0] + (um2 + xu[2]), a);
        ls += a * xv[0];
        // r=1
        a = pfma(m01, s1o[1] + (xu[0] + xu[2]), zero);
        a = pfma(m11, s1o[0] + s1o[2], a);
        a = pfma(m02, s2o[1] + (um1 + xu[3]), a);
        ls += a * xv[1];
        // r=2
        a = pfma(m01, s1o[2] + (xu[1] + xu[3]), zero);
        a = pfma(m11, s1o[1] + s1o[3], a);
        a = pfma(m02, s2o[2] + (xu[0] + xu[4]), a);
        ls += a * xv[2];
        // r=3
        a = pfma(m01, s1o[3] + (xu[2] + xu[4]), zero);
        a = pfma(m11, s1o[2] + s1o[4], a);
        a = pfma(m02, s2o[3] + (xu[1] + xu[5]), a);
        ls += a * xv[3];
        // r=4
        a = pfma(m01, s1o[4] + (xu[3] + xu[5]), zero);
        a = pfma(m11, s1o[3] + s1o[5], a);
        a = pfma(m02, s2o[4] + (xu[2] + up6), a);
        ls += a * xv[4];
        // r=5
        a = pfma(m01, s1o[5] + (xu[4] + up6), zero);
        a = pfma(m11, s1o[4] + s1p, a);
        a = pfma(m02, s2o[5] + (xu[3] + up7), a);
        ls += a * xv[5];
    }
    float lsum = ls.x + ls.y;

#pragma unroll
    for (int o = 1; o < 64; o <<= 1) lsum += __shfl_xor(lsum, o, 64);
    if (l == 0) sred[0][W] = lsum;
    __syncthreads();
    if (t == 0)
        atomicAdd(out, sred[0][0] + sred[0][1] + sred[0][2] + sred[0][3]);
}

extern "C" void kernel_launch(void* const* d_in, const int* in_sizes, int n_in,
                              void* d_out, int out_size, void* d_ws, size_t ws_size,
                              hipStream_t stream) {
    (void)in_sizes; (void)n_in; (void)out_size; (void)d_ws; (void)ws_size;
    const float* hm_gt = (const float*)d_in[0];
    const float* hm_pred = (const float*)d_in[1];
    const int* tops = (const int*)d_in[2];
    float* out = (float*)d_out;

    hipMemsetAsync(out, 0, sizeof(float), stream);
    sinkhorn_ilp<<<dim3(640), dim3(256), 0, stream>>>(hm_gt, hm_pred, tops, out);
}

// Round 15
// 164.730 us; speedup vs baseline: 1.1418x; 1.0135x over previous
//
#include <hip/hip_runtime.h>

#define TINYF 1e-8f
#define NITER 50

typedef __attribute__((ext_vector_type(2))) float v2f;

// Wave-wide DPP shifts (verified gfx950, R5-R12): 0x138 = wave_shr1 (lane i <- i-1,
// 0 into lane 0), 0x130 = wave_shl1 (lane i <- i+1, 0 into lane 63).
__device__ __forceinline__ float wWs(float v) {
    return __int_as_float(__builtin_amdgcn_update_dpp(0, __float_as_int(v), 0x138, 0xf, 0xf, true));
}
__device__ __forceinline__ float wEs(float v) {
    return __int_as_float(__builtin_amdgcn_update_dpp(0, __float_as_int(v), 0x130, 0xf, 0xf, true));
}
__device__ __forceinline__ v2f wW(v2f v) { v2f r; r.x = wWs(v.x); r.y = wWs(v.y); return r; }
__device__ __forceinline__ v2f wE(v2f v) { v2f r; r.x = wEs(v.x); r.y = wEs(v.y); return r; }
__device__ __forceinline__ v2f rcp2(v2f v) {
    v2f r; r.x = __builtin_amdgcn_rcpf(v.x); r.y = __builtin_amdgcn_rcpf(v.y); return r;
}
__device__ __forceinline__ v2f pfma(float k, v2f a, v2f c) {
    v2f kv; kv.x = k; kv.y = k;
    return __builtin_elementwise_fma(kv, a, c);
}

// R15 = R14 resubmitted verbatim (R14 hit an infra failure, never ran).
// R12 (verified best, 113.4us, exact 13-tap) + s_setprio(1) around the
// dense combine stages / setprio(0) around publish+barrier. Mechanism: waves
// of DIFFERENT blocks sharing a SIMD are at independent barrier phases; the
// priority hint favors a wave mid-combine over one headed into barrier-wait.
// Tap set frozen at 13 (R3/R13 both proved any drop is catastrophic).
// Bit-identical arithmetic to R12.
__global__ void __launch_bounds__(256)
__attribute__((amdgpu_waves_per_eu(3, 4)))
sinkhorn_pri(const float* __restrict__ hm_gt,
             const float* __restrict__ hm_pred,
             const int* __restrict__ tops,
             float* __restrict__ out) {
    __shared__ v2f ES[2][6][4][64];
    __shared__ float sred[2][4];

    const int t = threadIdx.x;
    const int W = t >> 6;                  // wave 0..3
    const int l = t & 63;                  // column (0..47 active)
    const bool act = (l < 48);

    // zero guards: .x of slot0 rows 2,3 (band -1) ; .y of slot5 rows 0,1 (band 8)
    {
        const int p = W >> 1, r = W & 1;
        ((float*)&ES[p][0][2 + r][l])[0] = 0.f;
        ((float*)&ES[p][5][r][l])[1] = 0.f;
    }

    const int blk = blockIdx.x;            // ((bi*8+rr)*5+cc)
    const int bi = blk / 40, rr = (blk / 5) % 8, cc = blk % 5;
    const int y0 = tops[(bi * 8 + rr) * 2 + 0];
    const int x0 = tops[(bi * 8 + rr) * 2 + 1];
    const float* srcA = hm_gt + (size_t)(bi * 5 + cc) * 25600;
    const float* srcB = hm_pred + (size_t)(bi * 5 + cc) * 25600;

    // ---- load own two 6-row column segments of both crops; block-reduce sums ----
    v2f va[6], vb[6];
    float sA = 0.f, sB = 0.f;
    const int rbx = y0 + 6 * W;            // .x band
    const int rby = y0 + 24 + 6 * W;       // .y band
#pragma unroll
    for (int r = 0; r < 6; ++r) {
        const int gx = (rbx + r) * 160 + x0 + l;
        const int gy = (rby + r) * 160 + x0 + l;
        va[r].x = act ? srcA[gx] : 0.f;
        va[r].y = act ? srcA[gy] : 0.f;
        vb[r].x = act ? srcB[gx] : 0.f;
        vb[r].y = act ? srcB[gy] : 0.f;
        sA += va[r].x + va[r].y;
        sB += vb[r].x + vb[r].y;
    }
#pragma unroll
    for (int o = 1; o < 64; o <<= 1) {
        sA += __shfl_xor(sA, o, 64);
        sB += __shfl_xor(sB, o, 64);
    }
    if (l == 0) { sred[0][W] = sA; sred[1][W] = sB; }
    __syncthreads();                       // also makes guard zeros visible
    sA = sred[0][0] + sred[0][1] + sred[0][2] + sred[0][3];
    sB = sred[1][0] + sred[1][1] + sred[1][2] + sred[1][3];
    const float nA = 1.0f / (sA + TINYF);
    const float nB = 1.0f / (sB + TINYF);
#pragma unroll
    for (int r = 0; r < 6; ++r) {
        va[r].x *= nA; va[r].y *= nA;
        vb[r].x *= nB; vb[r].y *= nB;
    }

    // Gibbs weights (same expressions as the verified rounds -> same values)
    const float e10 = expf(-1.0f / 0.1f);
    const float e2  = expf(-sqrtf(2.0f) / 0.1f);
    const float e20 = expf(-2.0f / 0.1f);
    const v2f tiny = {TINYF, TINYF};

    v2f xu[6], xv[6];
    const float u0 = 1.0f / 2304.0f;
#pragma unroll
    for (int r = 0; r < 6; ++r) { xu[r].x = act ? u0 : 0.f; xu[r].y = act ? u0 : 0.f; }

    // horizontal prep arrays of the CURRENT field (live across the barrier).
    // Stage-interleaved: 12 indep DPP, 6 adds, 12 indep DPP, 6 adds.
    v2f s1o[6], s2o[6];
    auto prep = [&](const v2f (&x)[6]) {
        v2f w1[6], e1[6];
#pragma unroll
        for (int r = 0; r < 6; ++r) { w1[r] = wW(x[r]); e1[r] = wE(x[r]); }
#pragma unroll
        for (int r = 0; r < 6; ++r) s1o[r] = w1[r] + e1[r];
        v2f w2[6], e2v[6];
#pragma unroll
        for (int r = 0; r < 6; ++r) { w2[r] = wW(w1[r]); e2v[r] = wE(e1[r]); }
#pragma unroll
        for (int r = 0; r < 6; ++r) s2o[r] = w2[r] + e2v[r];
    };

    // One half-iteration (caller issues __syncthreads() after). Stage form:
    // every stage = 6 independent chains. Bit-exact per-element vs R7/R12.
    auto half = [&](const v2f (&x)[6], v2f (&o)[6], const v2f (&co)[6],
                    int p, int q) {
        const v2f um1 = ES[p][W][3][l];        // band rows -1
        const v2f up6 = ES[p][W + 2][0][l];    // band rows +6
        const v2f um2 = ES[p][W][2][l];        // band rows -2
        const v2f up7 = ES[p][W + 2][1][l];    // band rows +7
        __builtin_amdgcn_s_setprio(1);         // favor mid-combine waves
        // S1: |dy|=1 vertical sums (x-only rows first: covers LDS latency)
        const v2f u1 = x[0] + x[2];
        const v2f u2 = x[1] + x[3];
        const v2f u3 = x[2] + x[4];
        const v2f u4 = x[3] + x[5];
        const v2f u0 = um1 + x[1];
        const v2f u5 = x[4] + up6;
        // halo horizontal sums (dep on um1/up6; 4 indep DPP + 2 adds)
        const v2f s1m = wW(um1) + wE(um1);
        const v2f s1p = wW(up6) + wE(up6);
        // S2: e10 level, 6 independent
        v2f a0, a1, a2, a3, a4, a5;
        a1 = pfma(e10, s1o[1] + u1, x[1]);
        a2 = pfma(e10, s1o[2] + u2, x[2]);
        a3 = pfma(e10, s1o[3] + u3, x[3]);
        a4 = pfma(e10, s1o[4] + u4, x[4]);
        a0 = pfma(e10, s1o[0] + u0, x[0]);
        a5 = pfma(e10, s1o[5] + u5, x[5]);
        // S3: e2 diagonal level, 6 independent
        a1 = pfma(e2, s1o[0] + s1o[2], a1);
        a2 = pfma(e2, s1o[1] + s1o[3], a2);
        a3 = pfma(e2, s1o[2] + s1o[4], a3);
        a4 = pfma(e2, s1o[3] + s1o[5], a4);
        a0 = pfma(e2, s1m + s1o[1], a0);
        a5 = pfma(e2, s1o[4] + s1p, a5);
        // S4: e20 level, 6 independent
        a1 = pfma(e20, s2o[1] + (um1 + x[3]), a1);
        a2 = pfma(e20, s2o[2] + (x[0] + x[4]), a2);
        a3 = pfma(e20, s2o[3] + (x[1] + x[5]), a3);
        a4 = pfma(e20, s2o[4] + (x[2] + up6), a4);
        a0 = pfma(e20, s2o[0] + (um2 + x[2]), a0);
        a5 = pfma(e20, s2o[5] + (x[3] + up7), a5);
        // S5: +tiny (6 indep), 12 back-to-back rcp, 6 muls
        a0 = a0 + tiny; a1 = a1 + tiny; a2 = a2 + tiny;
        a3 = a3 + tiny; a4 = a4 + tiny; a5 = a5 + tiny;
        const v2f r0 = rcp2(a0), r1 = rcp2(a1), r2 = rcp2(a2);
        const v2f r3 = rcp2(a3), r4 = rcp2(a4), r5 = rcp2(a5);
        o[0] = co[0] * r0; o[1] = co[1] * r1; o[2] = co[2] * r2;
        o[3] = co[3] * r3; o[4] = co[4] * r4; o[5] = co[5] * r5;
        __builtin_amdgcn_s_setprio(0);         // entering publish/barrier region
        // publish boundary rows (+ seams) to parity q
        ES[q][W + 1][0][l] = o[0];
        ES[q][W + 1][1][l] = o[1];
        ES[q][W + 1][2][l] = o[4];
        ES[q][W + 1][3][l] = o[5];
        if (W == 3) {
            ((float*)&ES[q][0][2][l])[1] = o[4].x;
            ((float*)&ES[q][0][3][l])[1] = o[5].x;
        }
        if (W == 0) {
            ((float*)&ES[q][5][0][l])[0] = o[0].y;
            ((float*)&ES[q][5][1][l])[0] = o[1].y;
        }
        // prep of the new field BEFORE the barrier (pure VALU, hides drain/skew)
        prep(o);
    };

    // seed parity 0 with u0 boundary rows; prep(xu); sync
    {
        ES[0][W + 1][0][l] = xu[0];
        ES[0][W + 1][1][l] = xu[1];
        ES[0][W + 1][2][l] = xu[4];
        ES[0][W + 1][3][l] = xu[5];
        if (W == 3) {
            ((float*)&ES[0][0][2][l])[1] = xu[4].x;
            ((float*)&ES[0][0][3][l])[1] = xu[5].x;
        }
        if (W == 0) {
            ((float*)&ES[0][5][0][l])[0] = xu[0].y;
            ((float*)&ES[0][5][1][l])[0] = xu[1].y;
        }
        prep(xu);
        __syncthreads();
    }

    // ---- Sinkhorn iterations: 1 barrier per half-iteration, pipelined ----
#pragma unroll 1
    for (int it = 0; it < NITER; ++it) {
        half(xu, xv, vb, 0, 1);
        __syncthreads();
        half(xv, xu, va, 1, 0);
        __syncthreads();
    }

    // ---- loss: (u @ M) . v, M = K .* dist (center 0; e5/e8 taps dropped) ----
    // Uses s1o/s2o = prep(xu) from the final half; halos from parity 0.
    const float s2f = sqrtf(2.0f);
    const float m01 = e10, m02 = e20 * 2.0f, m11 = e2 * s2f;
    v2f ls = {0.f, 0.f};
    {
        const v2f um1 = ES[0][W][3][l];
        const v2f up6 = ES[0][W + 2][0][l];
        const v2f um2 = ES[0][W][2][l];
        const v2f up7 = ES[0][W + 2][1][l];
        const v2f s1m = wW(um1) + wE(um1);
        const v2f s1p = wW(up6) + wE(up6);
        const v2f zero = {0.f, 0.f};
        v2f a;
        // r=0
        a = pfma(m01, s1o[0] + (um1 + xu[1]), zero);
        a = pfma(m11, s1m + s1o[1], a);
        a = pfma(m02, s2o[0] + (um2 + xu[2]), a);
        ls += a * xv[0];
        // r=1
        a = pfma(m01, s1o[1] + (xu[0] + xu[2]), zero);
        a = pfma(m11, s1o[0] + s1o[2], a);
        a = pfma(m02, s2o[1] + (um1 + xu[3]), a);
        ls += a * xv[1];
        // r=2
        a = pfma(m01, s1o[2] + (xu[1] + xu[3]), zero);
        a = pfma(m11, s1o[1] + s1o[3], a);
        a = pfma(m02, s2o[2] + (xu[0] + xu[4]), a);
        ls += a * xv[2];
        // r=3
        a = pfma(m01, s1o[3] + (xu[2] + xu[4]), zero);
        a = pfma(m11, s1o[2] + s1o[4], a);
        a = pfma(m02, s2o[3] + (xu[1] + xu[5]), a);
        ls += a * xv[3];
        // r=4
        a = pfma(m01, s1o[4] + (xu[3] + xu[5]), zero);
        a = pfma(m11, s1o[3] + s1o[5], a);
        a = pfma(m02, s2o[4] + (xu[2] + up6), a);
        ls += a * xv[4];
        // r=5
        a = pfma(m01, s1o[5] + (xu[4] + up6), zero);
        a = pfma(m11, s1o[4] + s1p, a);
        a = pfma(m02, s2o[5] + (xu[3] + up7), a);
        ls += a * xv[5];
    }
    float lsum = ls.x + ls.y;

#pragma unroll
    for (int o = 1; o < 64; o <<= 1) lsum += __shfl_xor(lsum, o, 64);
    if (l == 0) sred[0][W] = lsum;
    __syncthreads();
    if (t == 0)
        atomicAdd(out, sred[0][0] + sred[0][1] + sred[0][2] + sred[0][3]);
}

extern "C" void kernel_launch(void* const* d_in, const int* in_sizes, int n_in,
                              void* d_out, int out_size, void* d_ws, size_t ws_size,
                              hipStream_t stream) {
    (void)in_sizes; (void)n_in; (void)out_size; (void)d_ws; (void)ws_size;
    const float* hm_gt = (const float*)d_in[0];
    const float* hm_pred = (const float*)d_in[1];
    const int* tops = (const int*)d_in[2];
    float* out = (float*)d_out;

    hipMemsetAsync(out, 0, sizeof(float), stream);
    sinkhorn_pri<<<dim3(640), dim3(256), 0, stream>>>(hm_gt, hm_pred, tops, out);
}